// Round 2
// baseline (859.645 us; speedup 1.0000x reference)
//
#include <hip/hip_runtime.h>
#include <math.h>

// SubglacialDrainageSystem: 64x64 grid, N=4096, L=8064.
// Matrix-free Jacobi-preconditioned PIPELINED CG (Chronopoulos-Gear: one
// fused 2-dot reduction per iteration, SpMV applied to z, s=Ap by
// recurrence). z lives in LDS as fp32 (halves gather bytes, stride-1
// conflict-free); all recurrences/dots in fp64 registers.
// Single workgroup: 1024 threads x 4 nodes/thread.

#define NT   1024
#define KPER 4
#define NMAX (NT * KPER)

// Fused reduction of two doubles across the block. Entry barrier also
// fences the caller's preceding LDS reads; exit barrier fences the
// broadcast and makes it safe to overwrite the z-buffer afterwards.
__device__ __forceinline__ void block_reduce2(double& a, double& b, double* red) {
    for (int off = 32; off > 0; off >>= 1) {
        a += __shfl_down(a, off, 64);
        b += __shfl_down(b, off, 64);
    }
    const int lane = threadIdx.x & 63;
    const int wid  = threadIdx.x >> 6;
    __syncthreads();
    if (lane == 0) { red[2 * wid] = a; red[2 * wid + 1] = b; }
    __syncthreads();
    if (threadIdx.x < 64) {
        double s0 = (threadIdx.x < (NT / 64)) ? red[2 * threadIdx.x]     : 0.0;
        double s1 = (threadIdx.x < (NT / 64)) ? red[2 * threadIdx.x + 1] : 0.0;
        for (int off = 8; off > 0; off >>= 1) {
            s0 += __shfl_down(s0, off, 64);
            s1 += __shfl_down(s1, off, 64);
        }
        if (threadIdx.x == 0) { red[32] = s0; red[33] = s1; }
    }
    __syncthreads();
    a = red[32]; b = red[33];
}

__global__ __launch_bounds__(NT, 1)
void sds_solver(const float* __restrict__ base_pot,
                const float* __restrict__ ovb,
                const float* __restrict__ melt,
                const float* __restrict__ sheet,
                const float* __restrict__ pot,
                const float* __restrict__ svel,
                const float* __restrict__ llen,
                const int*   __restrict__ ltail,
                const int*   __restrict__ lhead,
                const int*   __restrict__ lan,
                const int*   __restrict__ inflow,
                const int*   __restrict__ dt_raw,
                float* __restrict__ out,
                int N, int L)
{
    // 32 KB buffer: link-coef staging (L fp32 = 32256 B) at setup,
    // then z-vector (N fp32 = 16 KB) during CG.
    __shared__ float  sbuf[8192];
    __shared__ double red[34];
    float* zf = sbuf;

    const int tid = threadIdx.x;

    const int dti = dt_raw[0];
    const float as_f = __int_as_float(dti);
    const double dtf = (as_f > 0.5f && as_f < 1.0e12f) ? (double)as_f : (double)dti;

    // ---- link coefficients c = -K * sheets^1.25 * len * |grad|^-0.5 ----
    for (int l = tid; l < L; l += NT) {
        const int t = ltail[l], h = lhead[l];
        const float sheets = 0.5f * (sheet[t] + sheet[h]);
        const float len = llen[l];
        const float grad = fabsf((pot[t] - pot[h]) / len);
        sbuf[l] = -0.01f * powf(sheets, 1.25f) * len / sqrtf(grad);
    }
    __syncthreads();

    // ---- per-node setup ----
    int    nbr[KPER][4];
    float  coef[KPER][4];
    double diag[KPER], invd[KPER], xv[KPER], rv[KPER], bb[KPER];
    double gg[KPER];
    bool   dirf[KPER];

    double gsum = 0.0, gcnt = 0.0;
    for (int k = 0; k < KPER; ++k) {
        const int n = tid + k * NT;
        double d = 0.0, g = 0.0;
        bool dir = false;
        if (n < N) {
            dir = (inflow[n] == 1);
            g = (double)base_pot[n] - (double)ovb[n];
        }
        for (int j = 0; j < 4; ++j) {
            float c = 0.0f; int nb = 0;
            if (n < N) {
                const int l = lan[n * 4 + j];
                if (l >= 0 && !dir) {
                    c  = sbuf[l];
                    nb = ltail[l] + lhead[l] - n;
                    d -= (double)c;
                }
            }
            coef[k][j] = c;
            nbr[k][j]  = nb;
        }
        bb[k]   = (n < N) ? (dir ? g : (double)melt[n]) : 0.0;
        gg[k]   = g;
        dirf[k] = dir;
        diag[k] = (dir || n >= N || d == 0.0) ? 1.0 : d;
        invd[k] = 1.0 / diag[k];
        if (dir) { gsum += g; gcnt += 1.0; }
    }
    __syncthreads();                 // coef staging reads done; sbuf reusable

    block_reduce2(gsum, gcnt, red);
    const double gmean = gsum / (gcnt > 0.0 ? gcnt : 1.0);

    // ---- x0: Dirichlet lift + boundary-mean interior; rounded to fp32 so
    //      the register copy matches what neighbors gather from LDS.
    for (int k = 0; k < KPER; ++k) {
        const int n = tid + k * NT;
        const float x0f = (float)(dirf[k] ? gg[k] : gmean);
        xv[k] = (double)x0f;
        if (n < N) zf[n] = x0f;
    }
    __syncthreads();

    // ---- r0 = b - A x0 ; z0 = round_f32(r0/diag) ----
    double zv[KPER], pv[KPER], sv_[KPER];
    for (int k = 0; k < KPER; ++k) {
        double s = diag[k] * xv[k];
        #pragma unroll
        for (int j = 0; j < 4; ++j)
            s += (double)coef[k][j] * (double)zf[nbr[k][j]];
        const int n = tid + k * NT;
        rv[k] = (n < N) ? (bb[k] - s) : 0.0;
        zv[k] = (double)(float)(rv[k] * invd[k]);
    }
    __syncthreads();                 // x0 gathers done
    for (int k = 0; k < KPER; ++k) {
        const int n = tid + k * NT;
        if (n < N) zf[n] = (float)zv[k];
    }
    __syncthreads();

    // ---- q0 = A z0 ; fused dots rho0=(r,z), mu0=(z,q) ----
    double qv[KPER];
    double rho = 0.0, mu = 0.0;
    for (int k = 0; k < KPER; ++k) {
        double s = diag[k] * zv[k];
        #pragma unroll
        for (int j = 0; j < 4; ++j)
            s += (double)coef[k][j] * (double)zf[nbr[k][j]];
        qv[k] = s;
        rho += rv[k] * zv[k];
        mu  += zv[k] * s;
    }
    block_reduce2(rho, mu, red);

    double alpha = (mu > 0.0) ? rho / mu : 0.0;
    for (int k = 0; k < KPER; ++k) { pv[k] = zv[k]; sv_[k] = qv[k]; }
    const double tol = rho * 1e-12 + 1e-300;

    // ---- pipelined CG main loop: ONE fused reduction per iteration ----
    if (alpha != 0.0)
    for (int it = 0; it < 500; ++it) {
        double rho_n = 0.0;
        mu = 0.0;
        for (int k = 0; k < KPER; ++k) {
            xv[k] += alpha * pv[k];
            rv[k] -= alpha * sv_[k];
            zv[k]  = (double)(float)(rv[k] * invd[k]);
        }
        // previous iteration's gathers were fenced by block_reduce2's exit
        // barrier -> safe to overwrite zf now.
        for (int k = 0; k < KPER; ++k) {
            const int n = tid + k * NT;
            if (n < N) zf[n] = (float)zv[k];
        }
        __syncthreads();
        for (int k = 0; k < KPER; ++k) {
            double s = diag[k] * zv[k];
            #pragma unroll
            for (int j = 0; j < 4; ++j)
                s += (double)coef[k][j] * (double)zf[nbr[k][j]];
            qv[k] = s;
            rho_n += rv[k] * zv[k];
            mu    += zv[k] * s;
        }
        block_reduce2(rho_n, mu, red);   // entry barrier fences gathers

        if (rho_n <= tol || !(rho_n > 0.0)) break;     // uniform
        const double beta = rho_n / rho;
        const double den  = mu - beta * rho_n / alpha;
        if (!(den > 0.0)) break;                       // uniform
        alpha = rho_n / den;
        rho   = rho_n;
        for (int k = 0; k < KPER; ++k) {
            pv[k]  = zv[k] + beta * pv[k];
            sv_[k] = qv[k] + beta * sv_[k];
        }
    }

    // ---- epilogue: new_potential, new_h ----
    for (int k = 0; k < KPER; ++k) {
        const int n = tid + k * NT;
        if (n >= N) continue;
        const double x = xv[k];
        out[n] = (float)x;

        float sv = 0.0f; int cnt = 0;
        for (int j = 0; j < 4; ++j) {
            const int l = lan[n * 4 + j];
            if (l >= 0) { sv += svel[l]; cnt++; }
        }
        const double sliding =
            fabs((double)sv / 31556926.0 / (double)(cnt > 0 ? cnt : 1));
        const double P   = (double)base_pot[n] - x;
        const double num = (double)sheet[n] + dtf * sliding * 0.1 / 2.0;
        const double den = 1.0 + dtf * (sliding / 2.0 + 5e-25 * P * P * P);
        out[N + n] = (float)(num / den);
    }
}

extern "C" void kernel_launch(void* const* d_in, const int* in_sizes, int n_in,
                              void* d_out, int out_size, void* d_ws, size_t ws_size,
                              hipStream_t stream) {
    const float* base_pot = (const float*)d_in[0];
    const float* ovb      = (const float*)d_in[1];
    const float* melt     = (const float*)d_in[2];
    const float* sheet    = (const float*)d_in[3];
    const float* pot      = (const float*)d_in[4];
    const float* svel     = (const float*)d_in[5];
    const float* llen     = (const float*)d_in[6];
    const int*   ltail    = (const int*)d_in[7];
    const int*   lhead    = (const int*)d_in[8];
    const int*   lan      = (const int*)d_in[9];
    const int*   inflow   = (const int*)d_in[10];
    const int*   dt_raw   = (const int*)d_in[11];
    float* out = (float*)d_out;
    const int N = in_sizes[0];
    const int L = in_sizes[5];

    hipLaunchKernelGGL(sds_solver, dim3(1), dim3(NT), 0, stream,
                       base_pot, ovb, melt, sheet, pot, svel, llen,
                       ltail, lhead, lan, inflow, dt_raw, out, N, L);
}

// Round 3
// 348.043 us; speedup vs baseline: 2.4699x; 2.4699x over previous
//
#include <hip/hip_runtime.h>
#include <math.h>

// SubglacialDrainageSystem, 64x64 grid (N=4096, L=8064), single workgroup.
// Geometry-aware Jacobi-PCG (pipelined / Chronopoulos-Gear):
//  - thread t owns 8 CONTIGUOUS nodes of one row -> E/W neighbors from
//    registers, N/S via two aligned float4 LDS reads. No scattered gathers.
//  - per-node W/E/N/S coefficients scattered once into LDS, then registers.
//  - 2 barriers per iteration (z-write fence + reduction fence);
//    reduction: wave shuffle -> 8 partials -> barrier -> per-thread sum of
//    8 broadcast values (ping-pong buffers, no extra fences).
//  - SpMV fp32, recurrences/dots fp64, tol = rho0*1e-9 (error << threshold).

#define NT   512
#define NPT  8
#define NN   4096
#define MAXIT 600

__global__ __launch_bounds__(NT, 1)
void sds_solver(const float* __restrict__ base_pot,
                const float* __restrict__ ovb,
                const float* __restrict__ melt,
                const float* __restrict__ sheet,
                const float* __restrict__ pot,
                const float* __restrict__ svel,
                const float* __restrict__ llen,
                const int*   __restrict__ ltail,
                const int*   __restrict__ lhead,
                const int*   __restrict__ lan,
                const int*   __restrict__ inflow,
                const int*   __restrict__ dt_raw,
                float* __restrict__ out,
                int N, int L)
{
    __shared__ float  zbuf[64 + NN + 64];   // padded z (row halo = zeros)
    __shared__ float  cWა[NN], cEა[NN], cNა[NN], cSა[NN];
    __shared__ double redp[2][16];          // ping-pong dot partials
    __shared__ double redg[16];             // one-time gmean reduce

    const int tid  = threadIdx.x;
    const int lane = tid & 63;
    const int wid  = tid >> 6;
    const int m    = tid * NPT;             // first node of this thread

    if (N != NN) return;

    const int dti = dt_raw[0];
    const float as_f = __int_as_float(dti);
    const double dtf = (as_f > 0.5f && as_f < 1.0e12f) ? (double)as_f : (double)dti;

    // ---- zero coef arrays + z halo ----
    for (int i = tid; i < NN; i += NT) {
        cWა[i] = 0.0f; cEა[i] = 0.0f; cNა[i] = 0.0f; cSა[i] = 0.0f;
    }
    if (tid < 64) { zbuf[tid] = 0.0f; zbuf[64 + NN + tid] = 0.0f; }
    __syncthreads();

    // ---- per-link coefficient scatter: c = -K*sheets^1.25*len*|grad|^-0.5
    for (int l = tid; l < L; l += NT) {
        const int t = ltail[l], h = lhead[l];
        const float sheets = 0.5f * (sheet[t] + sheet[h]);
        const float len = llen[l];
        const float grad = fabsf((pot[t] - pot[h]) / len);
        const float c = -0.01f * powf(sheets, 1.25f) * len / sqrtf(grad);
        const bool dt_ = (inflow[t] == 1);
        const bool dh_ = (inflow[h] == 1);
        if (h - t == 1) {            // horizontal link (t, t+1)
            cEა[t] = dt_ ? 0.0f : c;
            cWა[h] = dh_ ? 0.0f : c;
        } else {                     // vertical link (t, t+64)
            cSა[t] = dt_ ? 0.0f : c;
            cNა[h] = dh_ ? 0.0f : c;
        }
    }
    __syncthreads();

    // ---- per-node setup ----
    float cw[NPT], ce[NPT], cn[NPT], cs[NPT], dgf[NPT];
    double invd[NPT], bb[NPT], gg[NPT], xv[NPT];
    bool dirf[NPT];
    {
        const float4 w0 = *(const float4*)&cWა[m], w1 = *(const float4*)&cWა[m+4];
        const float4 e0 = *(const float4*)&cEა[m], e1 = *(const float4*)&cEა[m+4];
        const float4 n0 = *(const float4*)&cNა[m], n1 = *(const float4*)&cNა[m+4];
        const float4 s0 = *(const float4*)&cSა[m], s1 = *(const float4*)&cSა[m+4];
        cw[0]=w0.x;cw[1]=w0.y;cw[2]=w0.z;cw[3]=w0.w;cw[4]=w1.x;cw[5]=w1.y;cw[6]=w1.z;cw[7]=w1.w;
        ce[0]=e0.x;ce[1]=e0.y;ce[2]=e0.z;ce[3]=e0.w;ce[4]=e1.x;ce[5]=e1.y;ce[6]=e1.z;ce[7]=e1.w;
        cn[0]=n0.x;cn[1]=n0.y;cn[2]=n0.z;cn[3]=n0.w;cn[4]=n1.x;cn[5]=n1.y;cn[6]=n1.z;cn[7]=n1.w;
        cs[0]=s0.x;cs[1]=s0.y;cs[2]=s0.z;cs[3]=s0.w;cs[4]=s1.x;cs[5]=s1.y;cs[6]=s1.z;cs[7]=s1.w;
    }
    double gsum = 0.0, gcnt = 0.0;
    #pragma unroll
    for (int k = 0; k < NPT; ++k) {
        const int n = m + k;
        const bool dir = (inflow[n] == 1);
        const double g = (double)base_pot[n] - (double)ovb[n];
        const double d = -((double)cw[k] + (double)ce[k] + (double)cn[k] + (double)cs[k]);
        const double dg = (dir || d == 0.0) ? 1.0 : d;
        dgf[k]  = (float)dg;
        invd[k] = 1.0 / dg;
        bb[k]   = dir ? g : (double)melt[n];
        gg[k]   = g;
        dirf[k] = dir;
        if (dir) { gsum += g; gcnt += 1.0; }
    }
    // one-time 2-value reduction (own buffer, internal barrier)
    {
        #pragma unroll
        for (int off = 32; off > 0; off >>= 1) {
            gsum += __shfl_down(gsum, off, 64);
            gcnt += __shfl_down(gcnt, off, 64);
        }
        if (lane == 0) { redg[2*wid] = gsum; redg[2*wid+1] = gcnt; }
        __syncthreads();
        gsum = 0.0; gcnt = 0.0;
        #pragma unroll
        for (int w = 0; w < NT/64; ++w) { gsum += redg[2*w]; gcnt += redg[2*w+1]; }
    }
    const double gmean = gsum / (gcnt > 0.0 ? gcnt : 1.0);

    // ---- x0: Dirichlet lift + boundary-mean interior (fp32-rounded) ----
    float zr[NPT];
    #pragma unroll
    for (int k = 0; k < NPT; ++k) {
        const float x0f = (float)(dirf[k] ? gg[k] : gmean);
        xv[k] = (double)x0f;
        zr[k] = x0f;
    }
    *(float4*)&zbuf[64+m]   = make_float4(zr[0],zr[1],zr[2],zr[3]);
    *(float4*)&zbuf[64+m+4] = make_float4(zr[4],zr[5],zr[6],zr[7]);
    __syncthreads();

    // fp32 SpMV on current zbuf/zr -> qf
    float qf[NPT];
    auto spmv = [&]() {
        const float4 u0 = *(const float4*)&zbuf[m];
        const float4 u1 = *(const float4*)&zbuf[m+4];
        const float4 d0 = *(const float4*)&zbuf[m+128];
        const float4 d1 = *(const float4*)&zbuf[m+132];
        const float lw = zbuf[63 + m];
        const float re = zbuf[72 + m];
        const float up[NPT] = {u0.x,u0.y,u0.z,u0.w,u1.x,u1.y,u1.z,u1.w};
        const float dn[NPT] = {d0.x,d0.y,d0.z,d0.w,d1.x,d1.y,d1.z,d1.w};
        #pragma unroll
        for (int k = 0; k < NPT; ++k) {
            const float wv = k ? zr[k-1] : lw;
            const float ev = (k < NPT-1) ? zr[k+1] : re;
            qf[k] = dgf[k]*zr[k] + cw[k]*wv + ce[k]*ev + cn[k]*up[k] + cs[k]*dn[k];
        }
    };

    // ---- r0 = b - A x0 (dir rows pinned to 0) ; z0 ----
    double rv[NPT], zv[NPT];
    spmv();
    __syncthreads();                      // x0 gathers done; zbuf reusable
    #pragma unroll
    for (int k = 0; k < NPT; ++k) {
        rv[k] = dirf[k] ? 0.0 : (bb[k] - (double)qf[k]);
        zv[k] = (double)(float)(rv[k] * invd[k]);
        zr[k] = (float)zv[k];
    }
    *(float4*)&zbuf[64+m]   = make_float4(zr[0],zr[1],zr[2],zr[3]);
    *(float4*)&zbuf[64+m+4] = make_float4(zr[4],zr[5],zr[6],zr[7]);
    __syncthreads();

    // ---- q0 = A z0 ; rho0=(r,z), mu0=(z,q) ----
    spmv();
    double rho = 0.0, mu = 0.0;
    double qv[NPT], pv[NPT], sv_[NPT];
    #pragma unroll
    for (int k = 0; k < NPT; ++k) {
        qv[k] = (double)qf[k];
        rho += rv[k] * zv[k];
        mu  += zv[k] * qv[k];
    }
    {
        #pragma unroll
        for (int off = 32; off > 0; off >>= 1) {
            rho += __shfl_down(rho, off, 64);
            mu  += __shfl_down(mu,  off, 64);
        }
        if (lane == 0) { redp[0][2*wid] = rho; redp[0][2*wid+1] = mu; }
        __syncthreads();
        rho = 0.0; mu = 0.0;
        #pragma unroll
        for (int w = 0; w < NT/64; ++w) { rho += redp[0][2*w]; mu += redp[0][2*w+1]; }
    }
    double alpha = (mu > 0.0) ? rho / mu : 0.0;
    #pragma unroll
    for (int k = 0; k < NPT; ++k) { pv[k] = zv[k]; sv_[k] = qv[k]; }
    const double tol = rho * 1e-9 + 1e-300;

    // ---- pipelined PCG: 2 barriers / iteration ----
    if (alpha != 0.0)
    for (int it = 0; it < MAXIT; ++it) {
        #pragma unroll
        for (int k = 0; k < NPT; ++k) {
            xv[k] += alpha * pv[k];
            rv[k] -= alpha * sv_[k];
            zv[k]  = (double)(float)(rv[k] * invd[k]);
            zr[k]  = (float)zv[k];
        }
        // prior gathers fenced by previous reduction barrier -> safe write
        *(float4*)&zbuf[64+m]   = make_float4(zr[0],zr[1],zr[2],zr[3]);
        *(float4*)&zbuf[64+m+4] = make_float4(zr[4],zr[5],zr[6],zr[7]);
        __syncthreads();                  // B1: z visible

        spmv();
        double rho_n = 0.0; mu = 0.0;
        #pragma unroll
        for (int k = 0; k < NPT; ++k) {
            qv[k] = (double)qf[k];
            rho_n += rv[k] * zv[k];
            mu    += zv[k] * qv[k];
        }
        const int p = (it + 1) & 1;       // ping-pong partial buffer
        #pragma unroll
        for (int off = 32; off > 0; off >>= 1) {
            rho_n += __shfl_down(rho_n, off, 64);
            mu    += __shfl_down(mu,    off, 64);
        }
        if (lane == 0) { redp[p][2*wid] = rho_n; redp[p][2*wid+1] = mu; }
        __syncthreads();                  // B2: partials visible + gather fence
        rho_n = 0.0; mu = 0.0;
        #pragma unroll
        for (int w = 0; w < NT/64; ++w) { rho_n += redp[p][2*w]; mu += redp[p][2*w+1]; }

        if (rho_n <= tol || !(rho_n > 0.0)) break;          // uniform
        const double beta = rho_n / rho;
        const double den  = mu - beta * rho_n / alpha;
        if (!(den > 0.0)) break;                            // uniform
        alpha = rho_n / den;
        rho   = rho_n;
        #pragma unroll
        for (int k = 0; k < NPT; ++k) {
            pv[k]  = zv[k] + beta * pv[k];
            sv_[k] = qv[k] + beta * sv_[k];
        }
    }

    // ---- epilogue ----
    #pragma unroll
    for (int k = 0; k < NPT; ++k) {
        const int n = m + k;
        const double x = dirf[k] ? gg[k] : xv[k];
        out[n] = (float)x;

        float sv = 0.0f; int cnt = 0;
        for (int j = 0; j < 4; ++j) {
            const int l = lan[n * 4 + j];
            if (l >= 0) { sv += svel[l]; cnt++; }
        }
        const double sliding =
            fabs((double)sv / 31556926.0 / (double)(cnt > 0 ? cnt : 1));
        const double P   = (double)base_pot[n] - x;
        const double num = (double)sheet[n] + dtf * sliding * 0.1 / 2.0;
        const double den = 1.0 + dtf * (sliding / 2.0 + 5e-25 * P * P * P);
        out[NN + n] = (float)(num / den);
    }
}

extern "C" void kernel_launch(void* const* d_in, const int* in_sizes, int n_in,
                              void* d_out, int out_size, void* d_ws, size_t ws_size,
                              hipStream_t stream) {
    const float* base_pot = (const float*)d_in[0];
    const float* ovb      = (const float*)d_in[1];
    const float* melt     = (const float*)d_in[2];
    const float* sheet    = (const float*)d_in[3];
    const float* pot      = (const float*)d_in[4];
    const float* svel     = (const float*)d_in[5];
    const float* llen     = (const float*)d_in[6];
    const int*   ltail    = (const int*)d_in[7];
    const int*   lhead    = (const int*)d_in[8];
    const int*   lan      = (const int*)d_in[9];
    const int*   inflow   = (const int*)d_in[10];
    const int*   dt_raw   = (const int*)d_in[11];
    float* out = (float*)d_out;
    const int N = in_sizes[0];
    const int L = in_sizes[5];

    hipLaunchKernelGGL(sds_solver, dim3(1), dim3(NT), 0, stream,
                       base_pot, ovb, melt, sheet, pot, svel, llen,
                       ltail, lhead, lan, inflow, dt_raw, out, N, L);
}